// Round 9
// baseline (1015.431 us; speedup 1.0000x reference)
//
#include <hip/hip_runtime.h>
#include <hip/hip_bf16.h>

namespace {
constexpr int kN = 50000;   // nodes
constexpr int kE = 250000;  // edges
constexpr int kG = 2500;    // graphs
constexpr int NB = 8;       // nodes per conv block
constexpr int NBLK = (kN + 255) / 256;  // 196 node-blocks
constexpr int EBLK = (kE + 255) / 256;  // 977 edge-blocks

__device__ __forceinline__ float sigmoidf_(float x) { return 1.0f / (1.0f + expf(-x)); }

// fused: blocks [0,NBLK) -> h = relu(x@lin_w+b); blocks [NBLK, NBLK+EBLK) -> histograms
__global__ __launch_bounds__(256) void k_init_hist(const float* __restrict__ x,
                                                   const float* __restrict__ lin_w,
                                                   const float* __restrict__ lin_b,
                                                   float* __restrict__ h,
                                                   const int* __restrict__ src,
                                                   const int* __restrict__ dst,
                                                   int* __restrict__ cnt_s,
                                                   int* __restrict__ cnt_d) {
  if (blockIdx.x >= NBLK) {
    int e = (blockIdx.x - NBLK) * 256 + threadIdx.x;
    if (e < kE) {
      atomicAdd(&cnt_s[src[e]], 1);
      atomicAdd(&cnt_d[dst[e]], 1);
    }
    return;
  }
  __shared__ float ws[32 * 32];
  __shared__ float bs[32];
  for (int i = threadIdx.x; i < 1024; i += 256) ws[i] = lin_w[i];
  if (threadIdx.x < 32) bs[threadIdx.x] = lin_b[threadIdx.x];
  __syncthreads();
  int n = blockIdx.x * 256 + threadIdx.x;
  if (n >= kN) return;
  float xv[32];
  const float4* xp = (const float4*)(x + (size_t)n * 32);
#pragma unroll
  for (int i = 0; i < 8; ++i) {
    float4 v = xp[i];
    xv[4 * i + 0] = v.x; xv[4 * i + 1] = v.y; xv[4 * i + 2] = v.z; xv[4 * i + 3] = v.w;
  }
  float acc[32];
#pragma unroll
  for (int o = 0; o < 32; ++o) acc[o] = bs[o];
  for (int i = 0; i < 32; ++i) {
    float a = xv[i];
    const float4* wr = (const float4*)&ws[i * 32];
#pragma unroll
    for (int o4 = 0; o4 < 8; ++o4) {
      float4 w = wr[o4];
      acc[4 * o4 + 0] = fmaf(a, w.x, acc[4 * o4 + 0]);
      acc[4 * o4 + 1] = fmaf(a, w.y, acc[4 * o4 + 1]);
      acc[4 * o4 + 2] = fmaf(a, w.z, acc[4 * o4 + 2]);
      acc[4 * o4 + 3] = fmaf(a, w.w, acc[4 * o4 + 3]);
    }
  }
  float4* hp = (float4*)(h + (size_t)n * 32);
#pragma unroll
  for (int i = 0; i < 8; ++i) {
    float4 v;
    v.x = fmaxf(acc[4 * i + 0], 0.f);
    v.y = fmaxf(acc[4 * i + 1], 0.f);
    v.z = fmaxf(acc[4 * i + 2], 0.f);
    v.w = fmaxf(acc[4 * i + 3], 0.f);
    hp[i] = v;
  }
}

// eh row for sorted position pos: e = es_e[pos]; relu(ea[e]@w1+b1) -> ehs[pos] (coalesced write)
__global__ __launch_bounds__(256) void k_edge_h(const float* __restrict__ ea,
                                                const float* __restrict__ w1,
                                                const float* __restrict__ b1,
                                                const int* __restrict__ es_e,
                                                float* __restrict__ ehs) {
  __shared__ float ws[16 * 64];
  __shared__ float bs[64];
  for (int i = threadIdx.x; i < 1024; i += 256) ws[i] = w1[i];
  if (threadIdx.x < 64) bs[threadIdx.x] = b1[threadIdx.x];
  __syncthreads();
  int pos = blockIdx.x * 256 + threadIdx.x;
  if (pos >= kE) return;
  int e = es_e[pos];
  float av[16];
  const float4* ap = (const float4*)(ea + (size_t)e * 16);
#pragma unroll
  for (int i = 0; i < 4; ++i) {
    float4 v = ap[i];
    av[4 * i + 0] = v.x; av[4 * i + 1] = v.y; av[4 * i + 2] = v.z; av[4 * i + 3] = v.w;
  }
  float acc[64];
#pragma unroll
  for (int o = 0; o < 64; ++o) acc[o] = bs[o];
  for (int i = 0; i < 16; ++i) {
    float a = av[i];
    const float4* wr = (const float4*)&ws[i * 64];
#pragma unroll
    for (int o4 = 0; o4 < 16; ++o4) {
      float4 w = wr[o4];
      acc[4 * o4 + 0] = fmaf(a, w.x, acc[4 * o4 + 0]);
      acc[4 * o4 + 1] = fmaf(a, w.y, acc[4 * o4 + 1]);
      acc[4 * o4 + 2] = fmaf(a, w.z, acc[4 * o4 + 2]);
      acc[4 * o4 + 3] = fmaf(a, w.w, acc[4 * o4 + 3]);
    }
  }
  float4* op = (float4*)(ehs + (size_t)pos * 64);
#pragma unroll
  for (int i = 0; i < 16; ++i) {
    float4 v;
    v.x = fmaxf(acc[4 * i + 0], 0.f);
    v.y = fmaxf(acc[4 * i + 1], 0.f);
    v.z = fmaxf(acc[4 * i + 2], 0.f);
    v.w = fmaxf(acc[4 * i + 3], 0.f);
    op[i] = v;
  }
}

// ---- parallel 3-phase exclusive scan of cnt_s/cnt_d (grid.y selects array) ----
__global__ __launch_bounds__(256) void k_scan_blk(const int* __restrict__ cnt_s, int* __restrict__ offs_s,
                                                  const int* __restrict__ cnt_d, int* __restrict__ offs_d,
                                                  int* __restrict__ part) {
  const int arr = blockIdx.y;
  const int* cnt = arr ? cnt_d : cnt_s;
  int* offs = arr ? offs_d : offs_s;
  __shared__ int wsum[4];
  const int i = blockIdx.x * 256 + threadIdx.x;
  const int lane = threadIdx.x & 63, wv = threadIdx.x >> 6;
  int v = (i < kN) ? cnt[i] : 0;
  int x = v;
#pragma unroll
  for (int d = 1; d < 64; d <<= 1) {
    int t = __shfl_up(x, d, 64);
    if (lane >= d) x += t;
  }
  if (lane == 63) wsum[wv] = x;
  __syncthreads();
  int pre = 0;
#pragma unroll
  for (int w = 0; w < 3; ++w) pre += (w < wv) ? wsum[w] : 0;
  if (i < kN) offs[i] = pre + x - v;
  if (threadIdx.x == 255) part[arr * 256 + blockIdx.x] = pre + x;
}

__global__ __launch_bounds__(256) void k_scan_part(int* __restrict__ part,
                                                   int* __restrict__ offs_s,
                                                   int* __restrict__ offs_d) {
  const int arr = blockIdx.x;
  int* p = part + arr * 256;
  __shared__ int wsum[4];
  const int i = threadIdx.x;
  const int lane = i & 63, wv = i >> 6;
  int v = (i < NBLK) ? p[i] : 0;
  int x = v;
#pragma unroll
  for (int d = 1; d < 64; d <<= 1) {
    int t = __shfl_up(x, d, 64);
    if (lane >= d) x += t;
  }
  if (lane == 63) wsum[wv] = x;
  __syncthreads();
  int pre = 0;
#pragma unroll
  for (int w = 0; w < 3; ++w) pre += (w < wv) ? wsum[w] : 0;
  if (i < NBLK) p[i] = pre + x - v;
  if (i == NBLK - 1) (arr ? offs_d : offs_s)[kN] = pre + x;
}

// scan finalize + side jobs: starts (binary search) and w2t transpose
__global__ void k_scan_add(const int* __restrict__ part, int* __restrict__ offs_s,
                           int* __restrict__ offs_d, const int* __restrict__ batch,
                           int* __restrict__ starts, const float* __restrict__ w2,
                           float* __restrict__ w2t) {
  const int arr = blockIdx.y;
  int* offs = arr ? offs_d : offs_s;
  int i = blockIdx.x * 256 + threadIdx.x;
  if (i < kN) offs[i] += part[arr * 256 + blockIdx.x];
  if (arr == 0 && blockIdx.x < 10) {
    int g = blockIdx.x * 256 + threadIdx.x;
    if (g <= kG) {
      int lo = 0, hi = kN;
      while (lo < hi) {
        int mid = (lo + hi) >> 1;
        if (batch[mid] < g) lo = mid + 1; else hi = mid;
      }
      starts[g] = lo;
    }
  }
  int gid = (arr * gridDim.x + blockIdx.x) * 256 + threadIdx.x;
  if (gid < 65536) {
    int k = gid & 63, oa = gid >> 6;
    int o = oa & 31, a = oa >> 5;
    w2t[gid] = w2[(size_t)k * 1024 + a * 32 + o];
  }
}

// fused scatter: edge e -> src-sorted slot pos (es_e) + packed (dst-sorted slot pd | nl<<28)
__global__ void k_scatter(const int* __restrict__ src, const int* __restrict__ dst,
                          const int* __restrict__ offs_s, const int* __restrict__ offs_d,
                          int* __restrict__ cur_s, int* __restrict__ cur_d,
                          int* __restrict__ es_e, int* __restrict__ es_pk) {
  int e = blockIdx.x * blockDim.x + threadIdx.x;
  if (e >= kE) return;
  int s = src[e], d = dst[e];
  int pos = offs_s[s] + atomicAdd(&cur_s[s], 1);
  int pd = offs_d[d] + atomicAdd(&cur_d[d], 1);
  es_e[pos] = e;
  es_pk[pos] = pd | ((s & (NB - 1)) << 28);
}

// fused conv v5 (proven): two K-half passes, Ts pad-36, no shuffles/atomics;
// writes go to DST-SORTED msgbuf slot pd (scattered writes, coalesced agg reads).
__global__ __launch_bounds__(256, 4) void k_conv5(const float* __restrict__ h,
                                                  const float* __restrict__ ehs,
                                                  const float* __restrict__ w2t,
                                                  const float* __restrict__ b2,
                                                  const int* __restrict__ es_pk,
                                                  const int* __restrict__ offs,
                                                  float* __restrict__ msgbuf) {
  __shared__ float Ts[NB][32][36];
  __shared__ float hs[NB][32];
  __shared__ float hb2[NB][32];
  const int n0 = blockIdx.x * NB;
  const int t = threadIdx.x;
  const int nloc = t >> 5, o32 = t & 31;
  hs[nloc][o32] = h[(size_t)(n0 + nloc) * 32 + o32];
  __syncthreads();
  {  // hb2[n][o] = sum_a h[n,a] * b2[a*32+o]
    float a0 = 0.f;
#pragma unroll 8
    for (int a = 0; a < 32; ++a) a0 = fmaf(hs[nloc][a], b2[a * 32 + o32], a0);
    hb2[nloc][o32] = a0;
  }
  const int og = t >> 3;  // o (0..31) for T-build
  const int kq = t & 7;   // k-quad within half
  const int es = offs[n0], ee = offs[n0 + NB];
  const float* wp = w2t + og * 64 + kq * 4;
  const int kg = t >> 5;  // edge group

  for (int kh = 0; kh < 2; ++kh) {
    // ---- T-build (simple loads, compiler-scheduled)
    float4 acc[NB];
#pragma unroll
    for (int n = 0; n < NB; ++n) acc[n] = make_float4(0.f, 0.f, 0.f, 0.f);
    const float* wph = wp + kh * 32;
#pragma unroll 2
    for (int a4 = 0; a4 < 8; ++a4) {
      const float* wa = wph + (size_t)(a4 * 4) * 2048;
      float4 w0 = *(const float4*)(wa);
      float4 w1 = *(const float4*)(wa + 2048);
      float4 w2v = *(const float4*)(wa + 4096);
      float4 w3 = *(const float4*)(wa + 6144);
#pragma unroll
      for (int n = 0; n < NB; ++n) {
        float4 hv = *(const float4*)&hs[n][a4 * 4];
        acc[n].x = fmaf(hv.x, w0.x, acc[n].x); acc[n].y = fmaf(hv.x, w0.y, acc[n].y);
        acc[n].z = fmaf(hv.x, w0.z, acc[n].z); acc[n].w = fmaf(hv.x, w0.w, acc[n].w);
        acc[n].x = fmaf(hv.y, w1.x, acc[n].x); acc[n].y = fmaf(hv.y, w1.y, acc[n].y);
        acc[n].z = fmaf(hv.y, w1.z, acc[n].z); acc[n].w = fmaf(hv.y, w1.w, acc[n].w);
        acc[n].x = fmaf(hv.z, w2v.x, acc[n].x); acc[n].y = fmaf(hv.z, w2v.y, acc[n].y);
        acc[n].z = fmaf(hv.z, w2v.z, acc[n].z); acc[n].w = fmaf(hv.z, w2v.w, acc[n].w);
        acc[n].x = fmaf(hv.w, w3.x, acc[n].x); acc[n].y = fmaf(hv.w, w3.y, acc[n].y);
        acc[n].z = fmaf(hv.w, w3.z, acc[n].z); acc[n].w = fmaf(hv.w, w3.w, acc[n].w);
      }
    }
    if (kh) __syncthreads();  // pass-0 edge reads must finish before Ts overwrite
#pragma unroll
    for (int n = 0; n < NB; ++n) *(float4*)&Ts[n][og][kq * 4] = acc[n];
    __syncthreads();

    // ---- edge phase: block-strided; eh via group-uniform global reads; dst-slot writes
    for (int ei = es + kg; ei < ee; ei += 8) {
      const int pk = es_pk[ei];
      const int nl = pk >> 28;
      const int pd = pk & 0x0FFFFFFF;
      const float* ehp = ehs + (size_t)ei * 64 + kh * 32;
      float m0 = kh ? msgbuf[(size_t)pd * 32 + o32] : hb2[nl][o32];
      float m1 = 0.f, m2 = 0.f, m3 = 0.f;
      const float* tp = &Ts[nl][o32][0];
#pragma unroll
      for (int kq2 = 0; kq2 < 8; ++kq2) {
        float4 eq = *(const float4*)(ehp + kq2 * 4);   // group-uniform 16B
        float4 tv = *(const float4*)(tp + kq2 * 4);    // b128 LDS
        m0 = fmaf(eq.x, tv.x, m0);
        m1 = fmaf(eq.y, tv.y, m1);
        m2 = fmaf(eq.z, tv.z, m2);
        m3 = fmaf(eq.w, tv.w, m3);
      }
      msgbuf[(size_t)pd * 32 + o32] = (m0 + m1) + (m2 + m3);
    }
  }
}

// fused agg+GRU: 256 nodes/block. Phase 1: 8 groups x 32 dsts, contiguous dst-sorted
// msgbuf rows -> m = relu(mean) into m_s (stride 33, conflict-free). Phase 2: ALL 256
// threads run the GRU (thread-per-node), in-place h update.
__global__ __launch_bounds__(256) void k_aggru(const float* __restrict__ msgbuf,
                                               const int* __restrict__ offs_d,
                                               float* __restrict__ h,
                                               const float* __restrict__ Wih,
                                               const float* __restrict__ Whh,
                                               const float* __restrict__ bih,
                                               const float* __restrict__ bhh) {
  __shared__ float m_s[256][33];
  __shared__ float wih_s[96 * 32];
  __shared__ float whh_s[96 * 32];
  __shared__ float bih_s[96], bhh_s[96];
  for (int i = threadIdx.x; i < 96 * 32; i += 256) { wih_s[i] = Wih[i]; whh_s[i] = Whh[i]; }
  for (int i = threadIdx.x; i < 96; i += 256) { bih_s[i] = bih[i]; bhh_s[i] = bhh[i]; }
  const int grp = threadIdx.x >> 5, o = threadIdx.x & 31;
  const int nbase = blockIdx.x * 256;
  for (int j = 0; j < 32; ++j) {
    int dl = grp * 32 + j;
    int d = nbase + dl;
    if (d < kN) {
      int s = offs_d[d], e = offs_d[d + 1];
      float a0 = 0.f, a1 = 0.f;
      int jj = s;
      for (; jj + 1 < e; jj += 2) {
        a0 += msgbuf[(size_t)jj * 32 + o];
        a1 += msgbuf[(size_t)(jj + 1) * 32 + o];
      }
      if (jj < e) a0 += msgbuf[(size_t)jj * 32 + o];
      float dn = (float)(e - s);
      if (dn < 1.f) dn = 1.f;
      m_s[dl][o] = fmaxf((a0 + a1) / dn, 0.f);
    }
  }
  __syncthreads();
  const int n = nbase + threadIdx.x;
  if (n >= kN) return;
  float m[32], hv[32];
  const float4* hp = (const float4*)(h + (size_t)n * 32);
#pragma unroll
  for (int i = 0; i < 32; ++i) m[i] = m_s[threadIdx.x][i];
#pragma unroll
  for (int i = 0; i < 8; ++i) {
    float4 b = hp[i];
    hv[4 * i + 0] = b.x; hv[4 * i + 1] = b.y; hv[4 * i + 2] = b.z; hv[4 * i + 3] = b.w;
  }
  float rr[32], zz[32];
#pragma unroll 4
  for (int j = 0; j < 32; ++j) {
    float accA = bih_s[j], accB = bhh_s[j];
    const float4* wi = (const float4*)&wih_s[j * 32];
    const float4* wh = (const float4*)&whh_s[j * 32];
#pragma unroll
    for (int i = 0; i < 8; ++i) {
      float4 a = wi[i], b = wh[i];
      accA = fmaf(m[4 * i + 0], a.x, accA); accA = fmaf(m[4 * i + 1], a.y, accA);
      accA = fmaf(m[4 * i + 2], a.z, accA); accA = fmaf(m[4 * i + 3], a.w, accA);
      accB = fmaf(hv[4 * i + 0], b.x, accB); accB = fmaf(hv[4 * i + 1], b.y, accB);
      accB = fmaf(hv[4 * i + 2], b.z, accB); accB = fmaf(hv[4 * i + 3], b.w, accB);
    }
    rr[j] = sigmoidf_(accA + accB);
  }
#pragma unroll 4
  for (int j = 0; j < 32; ++j) {
    int row = 32 + j;
    float accA = bih_s[row], accB = bhh_s[row];
    const float4* wi = (const float4*)&wih_s[row * 32];
    const float4* wh = (const float4*)&whh_s[row * 32];
#pragma unroll
    for (int i = 0; i < 8; ++i) {
      float4 a = wi[i], b = wh[i];
      accA = fmaf(m[4 * i + 0], a.x, accA); accA = fmaf(m[4 * i + 1], a.y, accA);
      accA = fmaf(m[4 * i + 2], a.z, accA); accA = fmaf(m[4 * i + 3], a.w, accA);
      accB = fmaf(hv[4 * i + 0], b.x, accB); accB = fmaf(hv[4 * i + 1], b.y, accB);
      accB = fmaf(hv[4 * i + 2], b.z, accB); accB = fmaf(hv[4 * i + 3], b.w, accB);
    }
    zz[j] = sigmoidf_(accA + accB);
  }
#pragma unroll 4
  for (int j = 0; j < 32; ++j) {
    int row = 64 + j;
    float accA = bih_s[row], accB = bhh_s[row];
    const float4* wi = (const float4*)&wih_s[row * 32];
    const float4* wh = (const float4*)&whh_s[row * 32];
#pragma unroll
    for (int i = 0; i < 8; ++i) {
      float4 a = wi[i], b = wh[i];
      accA = fmaf(m[4 * i + 0], a.x, accA); accA = fmaf(m[4 * i + 1], a.y, accA);
      accA = fmaf(m[4 * i + 2], a.z, accA); accA = fmaf(m[4 * i + 3], a.w, accA);
      accB = fmaf(hv[4 * i + 0], b.x, accB); accB = fmaf(hv[4 * i + 1], b.y, accB);
      accB = fmaf(hv[4 * i + 2], b.z, accB); accB = fmaf(hv[4 * i + 3], b.w, accB);
    }
    float ng = tanhf(accA + rr[j] * accB);
    zz[j] = (1.f - zz[j]) * ng + zz[j] * hv[j];
  }
  float4* hw = (float4*)(h + (size_t)n * 32);
#pragma unroll
  for (int i = 0; i < 8; ++i)
    hw[i] = make_float4(zz[4 * i + 0], zz[4 * i + 1], zz[4 * i + 2], zz[4 * i + 3]);
}

// fused Set2Set (3 steps of LSTM + softmax attention pooling) + prediction.
__global__ __launch_bounds__(256) void k_s2s(const float* __restrict__ h,
                                             const int* __restrict__ starts,
                                             const float* __restrict__ lwih,
                                             const float* __restrict__ lwhh,
                                             const float* __restrict__ lbih,
                                             const float* __restrict__ lbhh,
                                             const float* __restrict__ pw,
                                             const float* __restrict__ pb,
                                             float* __restrict__ out) {
  __shared__ float wih_s[128][65];
  __shared__ float whh_s[128][33];
  __shared__ float bsum[128];
  for (int i = threadIdx.x; i < 128 * 64; i += 256) wih_s[i >> 6][i & 63] = lwih[i];
  for (int i = threadIdx.x; i < 128 * 32; i += 256) whh_s[i >> 5][i & 31] = lwhh[i];
  for (int i = threadIdx.x; i < 128; i += 256) bsum[i] = lbih[i] + lbhh[i];
  __syncthreads();
  const int g = blockIdx.x * 4 + (threadIdx.x >> 6);
  if (g >= kG) return;
  const int lane = threadIdx.x & 63;
  const int o = lane & 31;
  const int r1 = lane, r2 = lane + 64;
  const int s = starts[g], e = starts[g + 1];
  float c = 0.f, hl = 0.f, rp = 0.f;
  for (int step = 0; step < 3; ++step) {
    float v1 = bsum[r1], v2 = bsum[r2];
    for (int i = 0; i < 32; ++i) {
      float hli = __shfl(hl, i, 64);
      float rpi = __shfl(rp, i, 64);
      v1 = fmaf(wih_s[r1][i], hli, v1);
      v1 = fmaf(wih_s[r1][32 + i], rpi, v1);
      v1 = fmaf(whh_s[r1][i], hli, v1);
      v2 = fmaf(wih_s[r2][i], hli, v2);
      v2 = fmaf(wih_s[r2][32 + i], rpi, v2);
      v2 = fmaf(whh_s[r2][i], hli, v2);
    }
    float fg = sigmoidf_(__shfl(v1, 32 + o, 64));
    float og_ = sigmoidf_(__shfl(v2, 32 + o, 64));
    float ig = sigmoidf_(v1);
    float gg = tanhf(v2);
    c = fg * c + ig * gg;
    hl = og_ * tanhf(c);
    float q = __shfl(hl, o, 64);
    float mx = -3.0e38f;
    for (int nn = s; nn < e; nn += 2) {
      int n = nn + (lane >> 5);
      float val = (n < e) ? h[(size_t)n * 32 + o] * q : 0.f;
#pragma unroll
      for (int d = 16; d; d >>= 1) val += __shfl_xor(val, d, 32);
      if (n < e) mx = fmaxf(mx, val);
    }
    mx = fmaxf(mx, __shfl_xor(mx, 32, 64));
    float den = 0.f, racc = 0.f;
    for (int nn = s; nn < e; nn += 2) {
      int n = nn + (lane >> 5);
      float hvo = 0.f, val = 0.f;
      if (n < e) { hvo = h[(size_t)n * 32 + o]; val = hvo * q; }
#pragma unroll
      for (int d = 16; d; d >>= 1) val += __shfl_xor(val, d, 32);
      if (n < e) { float p = expf(val - mx); den += p; racc = fmaf(p, hvo, racc); }
    }
    den += __shfl_xor(den, 32, 64);
    racc += __shfl_xor(racc, 32, 64);
    rp = (e > s) ? racc / den : 0.f;
  }
  float acc = __shfl(hl, o, 64) * pw[o] + rp * pw[32 + o];
#pragma unroll
  for (int d = 16; d; d >>= 1) acc += __shfl_xor(acc, d, 32);
  if (lane == 0) out[g] = acc + pb[0];
}

}  // namespace

extern "C" void kernel_launch(void* const* d_in, const int* in_sizes, int n_in,
                              void* d_out, int out_size, void* d_ws, size_t ws_size,
                              hipStream_t stream) {
  const float* x     = (const float*)d_in[0];
  const int*   eidx  = (const int*)d_in[1];
  const float* eattr = (const float*)d_in[2];
  const int*   batch = (const int*)d_in[3];
  const float* lin_w = (const float*)d_in[4];
  const float* lin_b = (const float*)d_in[5];
  const float* e_w1  = (const float*)d_in[6];
  const float* e_b1  = (const float*)d_in[7];
  const float* e_w2  = (const float*)d_in[8];
  const float* e_b2  = (const float*)d_in[9];
  const float* gwih  = (const float*)d_in[10];
  const float* gwhh  = (const float*)d_in[11];
  const float* gbih  = (const float*)d_in[12];
  const float* gbhh  = (const float*)d_in[13];
  const float* lwih  = (const float*)d_in[14];
  const float* lwhh  = (const float*)d_in[15];
  const float* lbih  = (const float*)d_in[16];
  const float* lbhh  = (const float*)d_in[17];
  const float* pw    = (const float*)d_in[18];
  const float* pb    = (const float*)d_in[19];
  const int* srcp = eidx;
  const int* dstp = eidx + kE;

  float* ws = (float*)d_ws;
  size_t off = 0;
  auto alloc = [&](size_t nel) {
    float* p = ws + off;
    off += (nel + 255) & ~(size_t)255;
    return p;
  };
  float* hbuf   = alloc((size_t)kN * 32);
  float* ehs    = alloc((size_t)kE * 64);
  float* msgbuf = alloc((size_t)kE * 32);
  float* w2t    = alloc(65536);
  int* starts   = (int*)alloc(kG + 1);
  int* cnt_s    = (int*)alloc(kN);   // cnt_s, cnt_d, cur_s, cur_d contiguous (one memset)
  int* cnt_d    = (int*)alloc(kN);
  int* cur_s    = (int*)alloc(kN);
  int* cur_d    = (int*)alloc(kN);
  int* offs_s   = (int*)alloc(kN + 1);
  int* offs_d   = (int*)alloc(kN + 1);
  int* es_e     = (int*)alloc(kE);
  int* es_pk    = (int*)alloc(kE);
  int* part     = (int*)alloc(512);
  if (ws_size / 4 < off) return;

  // one memset over the 4 contiguous counter arrays
  hipMemsetAsync(cnt_s, 0, (size_t)((cur_d + ((kN + 255) & ~255)) - cnt_s) * 4, stream);

  k_init_hist<<<NBLK + EBLK, 256, 0, stream>>>(x, lin_w, lin_b, hbuf, srcp, dstp, cnt_s, cnt_d);
  {
    dim3 g(NBLK, 2);
    k_scan_blk<<<g, 256, 0, stream>>>(cnt_s, offs_s, cnt_d, offs_d, part);
    k_scan_part<<<2, 256, 0, stream>>>(part, offs_s, offs_d);
    k_scan_add<<<g, 256, 0, stream>>>(part, offs_s, offs_d, batch, starts, e_w2, w2t);
  }
  k_scatter<<<EBLK, 256, 0, stream>>>(srcp, dstp, offs_s, offs_d, cur_s, cur_d, es_e, es_pk);
  k_edge_h<<<EBLK, 256, 0, stream>>>(eattr, e_w1, e_b1, es_e, ehs);

  for (int step = 0; step < 3; ++step) {
    k_conv5<<<kN / NB, 256, 0, stream>>>(hbuf, ehs, w2t, e_b2, es_pk, offs_s, msgbuf);
    k_aggru<<<NBLK, 256, 0, stream>>>(msgbuf, offs_d, hbuf, gwih, gwhh, gbih, gbhh);
  }

  k_s2s<<<(kG + 3) / 4, 256, 0, stream>>>(hbuf, starts, lwih, lwhh, lbih, lbhh, pw, pb,
                                          (float*)d_out);
}

// Round 10
// 908.636 us; speedup vs baseline: 1.1175x; 1.1175x over previous
//
#include <hip/hip_runtime.h>
#include <hip/hip_bf16.h>

namespace {
constexpr int kN = 50000;   // nodes
constexpr int kE = 250000;  // edges
constexpr int kG = 2500;    // graphs
constexpr int NB = 8;       // nodes per conv block
constexpr int NBLK = (kN + 255) / 256;  // 196 node-blocks
constexpr int EBLK = (kE + 255) / 256;  // 977 edge-blocks

__device__ __forceinline__ float sigmoidf_(float x) { return 1.0f / (1.0f + expf(-x)); }

// fused: blocks [0,NBLK) -> h = relu(x@lin_w+b); blocks [NBLK, NBLK+EBLK) -> histograms
__global__ __launch_bounds__(256) void k_init_hist(const float* __restrict__ x,
                                                   const float* __restrict__ lin_w,
                                                   const float* __restrict__ lin_b,
                                                   float* __restrict__ h,
                                                   const int* __restrict__ src,
                                                   const int* __restrict__ dst,
                                                   int* __restrict__ cnt_s,
                                                   int* __restrict__ cnt_d) {
  if (blockIdx.x >= NBLK) {
    int e = (blockIdx.x - NBLK) * 256 + threadIdx.x;
    if (e < kE) {
      atomicAdd(&cnt_s[src[e]], 1);
      atomicAdd(&cnt_d[dst[e]], 1);
    }
    return;
  }
  __shared__ float ws[32 * 32];
  __shared__ float bs[32];
  for (int i = threadIdx.x; i < 1024; i += 256) ws[i] = lin_w[i];
  if (threadIdx.x < 32) bs[threadIdx.x] = lin_b[threadIdx.x];
  __syncthreads();
  int n = blockIdx.x * 256 + threadIdx.x;
  if (n >= kN) return;
  float xv[32];
  const float4* xp = (const float4*)(x + (size_t)n * 32);
#pragma unroll
  for (int i = 0; i < 8; ++i) {
    float4 v = xp[i];
    xv[4 * i + 0] = v.x; xv[4 * i + 1] = v.y; xv[4 * i + 2] = v.z; xv[4 * i + 3] = v.w;
  }
  float acc[32];
#pragma unroll
  for (int o = 0; o < 32; ++o) acc[o] = bs[o];
  for (int i = 0; i < 32; ++i) {
    float a = xv[i];
    const float4* wr = (const float4*)&ws[i * 32];
#pragma unroll
    for (int o4 = 0; o4 < 8; ++o4) {
      float4 w = wr[o4];
      acc[4 * o4 + 0] = fmaf(a, w.x, acc[4 * o4 + 0]);
      acc[4 * o4 + 1] = fmaf(a, w.y, acc[4 * o4 + 1]);
      acc[4 * o4 + 2] = fmaf(a, w.z, acc[4 * o4 + 2]);
      acc[4 * o4 + 3] = fmaf(a, w.w, acc[4 * o4 + 3]);
    }
  }
  float4* hp = (float4*)(h + (size_t)n * 32);
#pragma unroll
  for (int i = 0; i < 8; ++i) {
    float4 v;
    v.x = fmaxf(acc[4 * i + 0], 0.f);
    v.y = fmaxf(acc[4 * i + 1], 0.f);
    v.z = fmaxf(acc[4 * i + 2], 0.f);
    v.w = fmaxf(acc[4 * i + 3], 0.f);
    hp[i] = v;
  }
}

// eh row for sorted position pos: e = es_e[pos]; relu(ea[e]@w1+b1) -> ehs[pos] (coalesced write)
__global__ __launch_bounds__(256) void k_edge_h(const float* __restrict__ ea,
                                                const float* __restrict__ w1,
                                                const float* __restrict__ b1,
                                                const int* __restrict__ es_e,
                                                float* __restrict__ ehs) {
  __shared__ float ws[16 * 64];
  __shared__ float bs[64];
  for (int i = threadIdx.x; i < 1024; i += 256) ws[i] = w1[i];
  if (threadIdx.x < 64) bs[threadIdx.x] = b1[threadIdx.x];
  __syncthreads();
  int pos = blockIdx.x * 256 + threadIdx.x;
  if (pos >= kE) return;
  int e = es_e[pos];
  float av[16];
  const float4* ap = (const float4*)(ea + (size_t)e * 16);
#pragma unroll
  for (int i = 0; i < 4; ++i) {
    float4 v = ap[i];
    av[4 * i + 0] = v.x; av[4 * i + 1] = v.y; av[4 * i + 2] = v.z; av[4 * i + 3] = v.w;
  }
  float acc[64];
#pragma unroll
  for (int o = 0; o < 64; ++o) acc[o] = bs[o];
  for (int i = 0; i < 16; ++i) {
    float a = av[i];
    const float4* wr = (const float4*)&ws[i * 64];
#pragma unroll
    for (int o4 = 0; o4 < 16; ++o4) {
      float4 w = wr[o4];
      acc[4 * o4 + 0] = fmaf(a, w.x, acc[4 * o4 + 0]);
      acc[4 * o4 + 1] = fmaf(a, w.y, acc[4 * o4 + 1]);
      acc[4 * o4 + 2] = fmaf(a, w.z, acc[4 * o4 + 2]);
      acc[4 * o4 + 3] = fmaf(a, w.w, acc[4 * o4 + 3]);
    }
  }
  float4* op = (float4*)(ehs + (size_t)pos * 64);
#pragma unroll
  for (int i = 0; i < 16; ++i) {
    float4 v;
    v.x = fmaxf(acc[4 * i + 0], 0.f);
    v.y = fmaxf(acc[4 * i + 1], 0.f);
    v.z = fmaxf(acc[4 * i + 2], 0.f);
    v.w = fmaxf(acc[4 * i + 3], 0.f);
    op[i] = v;
  }
}

// ---- parallel 3-phase exclusive scan of cnt_s/cnt_d (grid.y selects array) ----
__global__ __launch_bounds__(256) void k_scan_blk(const int* __restrict__ cnt_s, int* __restrict__ offs_s,
                                                  const int* __restrict__ cnt_d, int* __restrict__ offs_d,
                                                  int* __restrict__ part) {
  const int arr = blockIdx.y;
  const int* cnt = arr ? cnt_d : cnt_s;
  int* offs = arr ? offs_d : offs_s;
  __shared__ int wsum[4];
  const int i = blockIdx.x * 256 + threadIdx.x;
  const int lane = threadIdx.x & 63, wv = threadIdx.x >> 6;
  int v = (i < kN) ? cnt[i] : 0;
  int x = v;
#pragma unroll
  for (int d = 1; d < 64; d <<= 1) {
    int t = __shfl_up(x, d, 64);
    if (lane >= d) x += t;
  }
  if (lane == 63) wsum[wv] = x;
  __syncthreads();
  int pre = 0;
#pragma unroll
  for (int w = 0; w < 3; ++w) pre += (w < wv) ? wsum[w] : 0;
  if (i < kN) offs[i] = pre + x - v;
  if (threadIdx.x == 255) part[arr * 256 + blockIdx.x] = pre + x;
}

__global__ __launch_bounds__(256) void k_scan_part(int* __restrict__ part,
                                                   int* __restrict__ offs_s,
                                                   int* __restrict__ offs_d) {
  const int arr = blockIdx.x;
  int* p = part + arr * 256;
  __shared__ int wsum[4];
  const int i = threadIdx.x;
  const int lane = i & 63, wv = i >> 6;
  int v = (i < NBLK) ? p[i] : 0;
  int x = v;
#pragma unroll
  for (int d = 1; d < 64; d <<= 1) {
    int t = __shfl_up(x, d, 64);
    if (lane >= d) x += t;
  }
  if (lane == 63) wsum[wv] = x;
  __syncthreads();
  int pre = 0;
#pragma unroll
  for (int w = 0; w < 3; ++w) pre += (w < wv) ? wsum[w] : 0;
  if (i < NBLK) p[i] = pre + x - v;
  if (i == NBLK - 1) (arr ? offs_d : offs_s)[kN] = pre + x;
}

// scan finalize + side jobs: starts (binary search) and w2t transpose
__global__ void k_scan_add(const int* __restrict__ part, int* __restrict__ offs_s,
                           int* __restrict__ offs_d, const int* __restrict__ batch,
                           int* __restrict__ starts, const float* __restrict__ w2,
                           float* __restrict__ w2t) {
  const int arr = blockIdx.y;
  int* offs = arr ? offs_d : offs_s;
  int i = blockIdx.x * 256 + threadIdx.x;
  if (i < kN) offs[i] += part[arr * 256 + blockIdx.x];
  if (arr == 0 && blockIdx.x < 10) {
    int g = blockIdx.x * 256 + threadIdx.x;
    if (g <= kG) {
      int lo = 0, hi = kN;
      while (lo < hi) {
        int mid = (lo + hi) >> 1;
        if (batch[mid] < g) lo = mid + 1; else hi = mid;
      }
      starts[g] = lo;
    }
  }
  int gid = (arr * gridDim.x + blockIdx.x) * 256 + threadIdx.x;
  if (gid < 65536) {
    int k = gid & 63, oa = gid >> 6;
    int o = oa & 31, a = oa >> 5;
    w2t[gid] = w2[(size_t)k * 1024 + a * 32 + o];
  }
}

// fused scatter: edge e -> src-sorted slot pos (es_e) + packed (dst-sorted slot pd | nl<<28)
__global__ void k_scatter(const int* __restrict__ src, const int* __restrict__ dst,
                          const int* __restrict__ offs_s, const int* __restrict__ offs_d,
                          int* __restrict__ cur_s, int* __restrict__ cur_d,
                          int* __restrict__ es_e, int* __restrict__ es_pk) {
  int e = blockIdx.x * blockDim.x + threadIdx.x;
  if (e >= kE) return;
  int s = src[e], d = dst[e];
  int pos = offs_s[s] + atomicAdd(&cur_s[s], 1);
  int pd = offs_d[d] + atomicAdd(&cur_d[d], 1);
  es_e[pos] = e;
  es_pk[pos] = pd | ((s & (NB - 1)) << 28);
}

// fused conv v5 (proven): two K-half passes, Ts pad-36, no shuffles/atomics;
// writes go to DST-SORTED msgbuf slot pd (scattered writes, coalesced agg reads).
__global__ __launch_bounds__(256, 4) void k_conv5(const float* __restrict__ h,
                                                  const float* __restrict__ ehs,
                                                  const float* __restrict__ w2t,
                                                  const float* __restrict__ b2,
                                                  const int* __restrict__ es_pk,
                                                  const int* __restrict__ offs,
                                                  float* __restrict__ msgbuf) {
  __shared__ float Ts[NB][32][36];
  __shared__ float hs[NB][32];
  __shared__ float hb2[NB][32];
  const int n0 = blockIdx.x * NB;
  const int t = threadIdx.x;
  const int nloc = t >> 5, o32 = t & 31;
  hs[nloc][o32] = h[(size_t)(n0 + nloc) * 32 + o32];
  __syncthreads();
  {  // hb2[n][o] = sum_a h[n,a] * b2[a*32+o]
    float a0 = 0.f;
#pragma unroll 8
    for (int a = 0; a < 32; ++a) a0 = fmaf(hs[nloc][a], b2[a * 32 + o32], a0);
    hb2[nloc][o32] = a0;
  }
  const int og = t >> 3;  // o (0..31) for T-build
  const int kq = t & 7;   // k-quad within half
  const int es = offs[n0], ee = offs[n0 + NB];
  const float* wp = w2t + og * 64 + kq * 4;
  const int kg = t >> 5;  // edge group

  for (int kh = 0; kh < 2; ++kh) {
    // ---- T-build (simple loads, compiler-scheduled)
    float4 acc[NB];
#pragma unroll
    for (int n = 0; n < NB; ++n) acc[n] = make_float4(0.f, 0.f, 0.f, 0.f);
    const float* wph = wp + kh * 32;
#pragma unroll 2
    for (int a4 = 0; a4 < 8; ++a4) {
      const float* wa = wph + (size_t)(a4 * 4) * 2048;
      float4 w0 = *(const float4*)(wa);
      float4 w1 = *(const float4*)(wa + 2048);
      float4 w2v = *(const float4*)(wa + 4096);
      float4 w3 = *(const float4*)(wa + 6144);
#pragma unroll
      for (int n = 0; n < NB; ++n) {
        float4 hv = *(const float4*)&hs[n][a4 * 4];
        acc[n].x = fmaf(hv.x, w0.x, acc[n].x); acc[n].y = fmaf(hv.x, w0.y, acc[n].y);
        acc[n].z = fmaf(hv.x, w0.z, acc[n].z); acc[n].w = fmaf(hv.x, w0.w, acc[n].w);
        acc[n].x = fmaf(hv.y, w1.x, acc[n].x); acc[n].y = fmaf(hv.y, w1.y, acc[n].y);
        acc[n].z = fmaf(hv.y, w1.z, acc[n].z); acc[n].w = fmaf(hv.y, w1.w, acc[n].w);
        acc[n].x = fmaf(hv.z, w2v.x, acc[n].x); acc[n].y = fmaf(hv.z, w2v.y, acc[n].y);
        acc[n].z = fmaf(hv.z, w2v.z, acc[n].z); acc[n].w = fmaf(hv.z, w2v.w, acc[n].w);
        acc[n].x = fmaf(hv.w, w3.x, acc[n].x); acc[n].y = fmaf(hv.w, w3.y, acc[n].y);
        acc[n].z = fmaf(hv.w, w3.z, acc[n].z); acc[n].w = fmaf(hv.w, w3.w, acc[n].w);
      }
    }
    if (kh) __syncthreads();  // pass-0 edge reads must finish before Ts overwrite
#pragma unroll
    for (int n = 0; n < NB; ++n) *(float4*)&Ts[n][og][kq * 4] = acc[n];
    __syncthreads();

    // ---- edge phase: block-strided; eh via group-uniform global reads; dst-slot writes
    for (int ei = es + kg; ei < ee; ei += 8) {
      const int pk = es_pk[ei];
      const int nl = pk >> 28;
      const int pd = pk & 0x0FFFFFFF;
      const float* ehp = ehs + (size_t)ei * 64 + kh * 32;
      float m0 = kh ? msgbuf[(size_t)pd * 32 + o32] : hb2[nl][o32];
      float m1 = 0.f, m2 = 0.f, m3 = 0.f;
      const float* tp = &Ts[nl][o32][0];
#pragma unroll
      for (int kq2 = 0; kq2 < 8; ++kq2) {
        float4 eq = *(const float4*)(ehp + kq2 * 4);   // group-uniform 16B
        float4 tv = *(const float4*)(tp + kq2 * 4);    // b128 LDS
        m0 = fmaf(eq.x, tv.x, m0);
        m1 = fmaf(eq.y, tv.y, m1);
        m2 = fmaf(eq.z, tv.z, m2);
        m3 = fmaf(eq.w, tv.w, m3);
      }
      msgbuf[(size_t)pd * 32 + o32] = (m0 + m1) + (m2 + m3);
    }
  }
}

// per-dst aggregation: msgbuf is dst-sorted -> CONTIGUOUS coalesced row reads.
__global__ __launch_bounds__(256) void k_agg(const float* __restrict__ msgbuf,
                                             const int* __restrict__ offs_d,
                                             float* __restrict__ m_out) {
  int d = blockIdx.x * 8 + (threadIdx.x >> 5);
  if (d >= kN) return;
  int o = threadIdx.x & 31;
  int s = offs_d[d], e = offs_d[d + 1];
  float a0 = 0.f, a1 = 0.f;
  int j = s;
  for (; j + 1 < e; j += 2) {
    a0 += msgbuf[(size_t)j * 32 + o];
    a1 += msgbuf[(size_t)(j + 1) * 32 + o];
  }
  if (j < e) a0 += msgbuf[(size_t)j * 32 + o];
  float dn = (float)(e - s);
  if (dn < 1.f) dn = 1.f;
  m_out[(size_t)d * 32 + o] = fmaxf((a0 + a1) / dn, 0.f);
}

// GRU cell, in-place h update; weights staged in LDS (broadcast reads)
__global__ __launch_bounds__(256) void k_gru(float* __restrict__ h, const float* __restrict__ m_in,
                                             const float* __restrict__ Wih, const float* __restrict__ Whh,
                                             const float* __restrict__ bih, const float* __restrict__ bhh) {
  __shared__ float wih_s[96 * 32];
  __shared__ float whh_s[96 * 32];
  __shared__ float bih_s[96], bhh_s[96];
  for (int i = threadIdx.x; i < 96 * 32; i += 256) { wih_s[i] = Wih[i]; whh_s[i] = Whh[i]; }
  for (int i = threadIdx.x; i < 96; i += 256) { bih_s[i] = bih[i]; bhh_s[i] = bhh[i]; }
  __syncthreads();
  int n = blockIdx.x * 256 + threadIdx.x;
  if (n >= kN) return;
  float m[32], hv[32];
  const float4* ap = (const float4*)(m_in + (size_t)n * 32);
  const float4* hp = (const float4*)(h + (size_t)n * 32);
#pragma unroll
  for (int i = 0; i < 8; ++i) {
    float4 a = ap[i];
    m[4 * i + 0] = a.x; m[4 * i + 1] = a.y; m[4 * i + 2] = a.z; m[4 * i + 3] = a.w;
    float4 b = hp[i];
    hv[4 * i + 0] = b.x; hv[4 * i + 1] = b.y; hv[4 * i + 2] = b.z; hv[4 * i + 3] = b.w;
  }
  float rr[32], zz[32];
#pragma unroll 4
  for (int j = 0; j < 32; ++j) {
    float accA = bih_s[j], accB = bhh_s[j];
    const float4* wi = (const float4*)&wih_s[j * 32];
    const float4* wh = (const float4*)&whh_s[j * 32];
#pragma unroll
    for (int i = 0; i < 8; ++i) {
      float4 a = wi[i], b = wh[i];
      accA = fmaf(m[4 * i + 0], a.x, accA); accA = fmaf(m[4 * i + 1], a.y, accA);
      accA = fmaf(m[4 * i + 2], a.z, accA); accA = fmaf(m[4 * i + 3], a.w, accA);
      accB = fmaf(hv[4 * i + 0], b.x, accB); accB = fmaf(hv[4 * i + 1], b.y, accB);
      accB = fmaf(hv[4 * i + 2], b.z, accB); accB = fmaf(hv[4 * i + 3], b.w, accB);
    }
    rr[j] = sigmoidf_(accA + accB);
  }
#pragma unroll 4
  for (int j = 0; j < 32; ++j) {
    int row = 32 + j;
    float accA = bih_s[row], accB = bhh_s[row];
    const float4* wi = (const float4*)&wih_s[row * 32];
    const float4* wh = (const float4*)&whh_s[row * 32];
#pragma unroll
    for (int i = 0; i < 8; ++i) {
      float4 a = wi[i], b = wh[i];
      accA = fmaf(m[4 * i + 0], a.x, accA); accA = fmaf(m[4 * i + 1], a.y, accA);
      accA = fmaf(m[4 * i + 2], a.z, accA); accA = fmaf(m[4 * i + 3], a.w, accA);
      accB = fmaf(hv[4 * i + 0], b.x, accB); accB = fmaf(hv[4 * i + 1], b.y, accB);
      accB = fmaf(hv[4 * i + 2], b.z, accB); accB = fmaf(hv[4 * i + 3], b.w, accB);
    }
    zz[j] = sigmoidf_(accA + accB);
  }
#pragma unroll 4
  for (int j = 0; j < 32; ++j) {
    int row = 64 + j;
    float accA = bih_s[row], accB = bhh_s[row];
    const float4* wi = (const float4*)&wih_s[row * 32];
    const float4* wh = (const float4*)&whh_s[row * 32];
#pragma unroll
    for (int i = 0; i < 8; ++i) {
      float4 a = wi[i], b = wh[i];
      accA = fmaf(m[4 * i + 0], a.x, accA); accA = fmaf(m[4 * i + 1], a.y, accA);
      accA = fmaf(m[4 * i + 2], a.z, accA); accA = fmaf(m[4 * i + 3], a.w, accA);
      accB = fmaf(hv[4 * i + 0], b.x, accB); accB = fmaf(hv[4 * i + 1], b.y, accB);
      accB = fmaf(hv[4 * i + 2], b.z, accB); accB = fmaf(hv[4 * i + 3], b.w, accB);
    }
    float ng = tanhf(accA + rr[j] * accB);
    zz[j] = (1.f - zz[j]) * ng + zz[j] * hv[j];
  }
  float4* hw = (float4*)(h + (size_t)n * 32);
#pragma unroll
  for (int i = 0; i < 8; ++i)
    hw[i] = make_float4(zz[4 * i + 0], zz[4 * i + 1], zz[4 * i + 2], zz[4 * i + 3]);
}

// fused Set2Set (3 steps of LSTM + softmax attention pooling) + prediction.
__global__ __launch_bounds__(256) void k_s2s(const float* __restrict__ h,
                                             const int* __restrict__ starts,
                                             const float* __restrict__ lwih,
                                             const float* __restrict__ lwhh,
                                             const float* __restrict__ lbih,
                                             const float* __restrict__ lbhh,
                                             const float* __restrict__ pw,
                                             const float* __restrict__ pb,
                                             float* __restrict__ out) {
  __shared__ float wih_s[128][65];
  __shared__ float whh_s[128][33];
  __shared__ float bsum[128];
  for (int i = threadIdx.x; i < 128 * 64; i += 256) wih_s[i >> 6][i & 63] = lwih[i];
  for (int i = threadIdx.x; i < 128 * 32; i += 256) whh_s[i >> 5][i & 31] = lwhh[i];
  for (int i = threadIdx.x; i < 128; i += 256) bsum[i] = lbih[i] + lbhh[i];
  __syncthreads();
  const int g = blockIdx.x * 4 + (threadIdx.x >> 6);
  if (g >= kG) return;
  const int lane = threadIdx.x & 63;
  const int o = lane & 31;
  const int r1 = lane, r2 = lane + 64;
  const int s = starts[g], e = starts[g + 1];
  float c = 0.f, hl = 0.f, rp = 0.f;
  for (int step = 0; step < 3; ++step) {
    float v1 = bsum[r1], v2 = bsum[r2];
    for (int i = 0; i < 32; ++i) {
      float hli = __shfl(hl, i, 64);
      float rpi = __shfl(rp, i, 64);
      v1 = fmaf(wih_s[r1][i], hli, v1);
      v1 = fmaf(wih_s[r1][32 + i], rpi, v1);
      v1 = fmaf(whh_s[r1][i], hli, v1);
      v2 = fmaf(wih_s[r2][i], hli, v2);
      v2 = fmaf(wih_s[r2][32 + i], rpi, v2);
      v2 = fmaf(whh_s[r2][i], hli, v2);
    }
    float fg = sigmoidf_(__shfl(v1, 32 + o, 64));
    float og_ = sigmoidf_(__shfl(v2, 32 + o, 64));
    float ig = sigmoidf_(v1);
    float gg = tanhf(v2);
    c = fg * c + ig * gg;
    hl = og_ * tanhf(c);
    float q = __shfl(hl, o, 64);
    float mx = -3.0e38f;
    for (int nn = s; nn < e; nn += 2) {
      int n = nn + (lane >> 5);
      float val = (n < e) ? h[(size_t)n * 32 + o] * q : 0.f;
#pragma unroll
      for (int d = 16; d; d >>= 1) val += __shfl_xor(val, d, 32);
      if (n < e) mx = fmaxf(mx, val);
    }
    mx = fmaxf(mx, __shfl_xor(mx, 32, 64));
    float den = 0.f, racc = 0.f;
    for (int nn = s; nn < e; nn += 2) {
      int n = nn + (lane >> 5);
      float hvo = 0.f, val = 0.f;
      if (n < e) { hvo = h[(size_t)n * 32 + o]; val = hvo * q; }
#pragma unroll
      for (int d = 16; d; d >>= 1) val += __shfl_xor(val, d, 32);
      if (n < e) { float p = expf(val - mx); den += p; racc = fmaf(p, hvo, racc); }
    }
    den += __shfl_xor(den, 32, 64);
    racc += __shfl_xor(racc, 32, 64);
    rp = (e > s) ? racc / den : 0.f;
  }
  float acc = __shfl(hl, o, 64) * pw[o] + rp * pw[32 + o];
#pragma unroll
  for (int d = 16; d; d >>= 1) acc += __shfl_xor(acc, d, 32);
  if (lane == 0) out[g] = acc + pb[0];
}

}  // namespace

extern "C" void kernel_launch(void* const* d_in, const int* in_sizes, int n_in,
                              void* d_out, int out_size, void* d_ws, size_t ws_size,
                              hipStream_t stream) {
  const float* x     = (const float*)d_in[0];
  const int*   eidx  = (const int*)d_in[1];
  const float* eattr = (const float*)d_in[2];
  const int*   batch = (const int*)d_in[3];
  const float* lin_w = (const float*)d_in[4];
  const float* lin_b = (const float*)d_in[5];
  const float* e_w1  = (const float*)d_in[6];
  const float* e_b1  = (const float*)d_in[7];
  const float* e_w2  = (const float*)d_in[8];
  const float* e_b2  = (const float*)d_in[9];
  const float* gwih  = (const float*)d_in[10];
  const float* gwhh  = (const float*)d_in[11];
  const float* gbih  = (const float*)d_in[12];
  const float* gbhh  = (const float*)d_in[13];
  const float* lwih  = (const float*)d_in[14];
  const float* lwhh  = (const float*)d_in[15];
  const float* lbih  = (const float*)d_in[16];
  const float* lbhh  = (const float*)d_in[17];
  const float* pw    = (const float*)d_in[18];
  const float* pb    = (const float*)d_in[19];
  const int* srcp = eidx;
  const int* dstp = eidx + kE;

  float* ws = (float*)d_ws;
  size_t off = 0;
  auto alloc = [&](size_t nel) {
    float* p = ws + off;
    off += (nel + 255) & ~(size_t)255;
    return p;
  };
  float* hbuf   = alloc((size_t)kN * 32);
  float* mbuf   = alloc((size_t)kN * 32);
  float* ehs    = alloc((size_t)kE * 64);
  float* msgbuf = alloc((size_t)kE * 32);
  float* w2t    = alloc(65536);
  int* starts   = (int*)alloc(kG + 1);
  int* cnt_s    = (int*)alloc(kN);   // cnt_s, cnt_d, cur_s, cur_d contiguous (one memset)
  int* cnt_d    = (int*)alloc(kN);
  int* cur_s    = (int*)alloc(kN);
  int* cur_d    = (int*)alloc(kN);
  int* offs_s   = (int*)alloc(kN + 1);
  int* offs_d   = (int*)alloc(kN + 1);
  int* es_e     = (int*)alloc(kE);
  int* es_pk    = (int*)alloc(kE);
  int* part     = (int*)alloc(512);
  if (ws_size / 4 < off) return;

  // one memset over the 4 contiguous counter arrays
  hipMemsetAsync(cnt_s, 0, (size_t)((cur_d + ((kN + 255) & ~255)) - cnt_s) * 4, stream);

  k_init_hist<<<NBLK + EBLK, 256, 0, stream>>>(x, lin_w, lin_b, hbuf, srcp, dstp, cnt_s, cnt_d);
  {
    dim3 g(NBLK, 2);
    k_scan_blk<<<g, 256, 0, stream>>>(cnt_s, offs_s, cnt_d, offs_d, part);
    k_scan_part<<<2, 256, 0, stream>>>(part, offs_s, offs_d);
    k_scan_add<<<g, 256, 0, stream>>>(part, offs_s, offs_d, batch, starts, e_w2, w2t);
  }
  k_scatter<<<EBLK, 256, 0, stream>>>(srcp, dstp, offs_s, offs_d, cur_s, cur_d, es_e, es_pk);
  k_edge_h<<<EBLK, 256, 0, stream>>>(eattr, e_w1, e_b1, es_e, ehs);

  for (int step = 0; step < 3; ++step) {
    k_conv5<<<kN / NB, 256, 0, stream>>>(hbuf, ehs, w2t, e_b2, es_pk, offs_s, msgbuf);
    k_agg<<<(kN + 7) / 8, 256, 0, stream>>>(msgbuf, offs_d, mbuf);
    k_gru<<<(kN + 255) / 256, 256, 0, stream>>>(hbuf, mbuf, gwih, gwhh, gbih, gbhh);
  }

  k_s2s<<<(kG + 3) / 4, 256, 0, stream>>>(hbuf, starts, lwih, lwhh, lbih, lbhh, pw, pb,
                                          (float*)d_out);
}